// Round 9
// baseline (336.092 us; speedup 1.0000x reference)
//
#include <hip/hip_runtime.h>

#define N_NODES 100000
#define N_PAD   100032
#define N_EDGES 1600000
#define HID 128
#define N_PRED 8

#define BSHIFT 7                       // 128 nodes per bucket
#define NBUCK  782                     // ceil(100000/128)
#define NB2    1564                    // dst buckets ++ src buckets
#define CHUNK  4096                    // edges per sort block
#define NCHUNK 391                     // ceil(1600000/4096)
#define NG     8                       // XCD groups (block->XCD ~ blockIdx%8)
#define MAXB   3072                    // LDS capacity per bucket (avg 2047)
#define ECAP   1184                    // LDS edge-index cap per 64-row block (avg 1024, sigma 32)

#define LROW 136                       // LDS row stride in shorts (128 + 8 pad)

typedef __attribute__((ext_vector_type(8))) short short8;
typedef __attribute__((ext_vector_type(4))) float f32x4;
typedef __attribute__((ext_vector_type(2))) float f32x2;

__device__ __forceinline__ unsigned short f2bf(float f) {
    union { float f; unsigned u; } c; c.f = f;
    unsigned u = c.u;
    u += 0x7fffu + ((u >> 16) & 1u);   // RNE
    return (unsigned short)(u >> 16);
}

__device__ __forceinline__ unsigned char f2fp8(float v) {
    unsigned w = __builtin_amdgcn_cvt_pk_fp8_f32(v, v, 0, false);
    return (unsigned char)(w & 0xff);
}

// ============ CSR build: dual bucket sort (dst for CSR, src for out-degree) ============

// blocks [0,NCHUNK): per-chunk histogram of dst buckets [0,NBUCK) and src buckets [NBUCK,NB2)
// blocks [NCHUNK, NCHUNK+12): repack 3 weights (fp32 KxN) into bf16 B-fragment order
__global__ void bucket_hist(const int4* __restrict__ src4, const int4* __restrict__ dst4,
                            unsigned* __restrict__ blockHist,
                            const float* __restrict__ W0, const float* __restrict__ W1,
                            const float* __restrict__ W2,
                            unsigned short* __restrict__ Wp0, unsigned short* __restrict__ Wp1,
                            unsigned short* __restrict__ Wp2) {
    if (blockIdx.x >= NCHUNK) {        // weight repack: 4 blocks x 512 thr per weight
        int rel = blockIdx.x - NCHUNK;
        int which = rel >> 2;
        const float* W = which == 0 ? W0 : which == 1 ? W1 : W2;
        unsigned short* Wp = which == 0 ? Wp0 : which == 1 ? Wp1 : Wp2;
        int tid = (rel & 3) * 512 + threadIdx.x;   // [0,2048)
        int tile = tid >> 6, lane = tid & 63;
        int n_tile = tile >> 2, k_tile = tile & 3;
        int n = n_tile * 16 + (lane & 15);
        int k0 = k_tile * 32 + (lane >> 4) * 8;
        unsigned short v[8];
#pragma unroll
        for (int j = 0; j < 8; ++j)
            v[j] = f2bf(W[(size_t)(k0 + j) * 128 + n]);
        uint4 o;
        o.x = (unsigned)v[0] | ((unsigned)v[1] << 16);
        o.y = (unsigned)v[2] | ((unsigned)v[3] << 16);
        o.z = (unsigned)v[4] | ((unsigned)v[5] << 16);
        o.w = (unsigned)v[6] | ((unsigned)v[7] << 16);
        *(uint4*)&Wp[(size_t)(tile * 64 + lane) * 8] = o;
        return;
    }
    __shared__ unsigned hist[NB2];
    for (int i = threadIdx.x; i < NB2; i += 512) hist[i] = 0u;
    __syncthreads();
    int base4 = blockIdx.x * (CHUNK / 4);
    int lim4 = min(base4 + CHUNK / 4, N_EDGES / 4);
    for (int e = base4 + threadIdx.x; e < lim4; e += 512) {
        int4 d = dst4[e];
        int4 s = src4[e];
        atomicAdd(&hist[((unsigned)d.x) >> BSHIFT], 1u);
        atomicAdd(&hist[((unsigned)d.y) >> BSHIFT], 1u);
        atomicAdd(&hist[((unsigned)d.z) >> BSHIFT], 1u);
        atomicAdd(&hist[((unsigned)d.w) >> BSHIFT], 1u);
        atomicAdd(&hist[NBUCK + (((unsigned)s.x) >> BSHIFT)], 1u);
        atomicAdd(&hist[NBUCK + (((unsigned)s.y) >> BSHIFT)], 1u);
        atomicAdd(&hist[NBUCK + (((unsigned)s.z) >> BSHIFT)], 1u);
        atomicAdd(&hist[NBUCK + (((unsigned)s.w) >> BSHIFT)], 1u);
    }
    __syncthreads();
    for (int i = threadIdx.x; i < NB2; i += 512)
        blockHist[(size_t)i * NCHUNK + blockIdx.x] = hist[i];   // bucket-major
}

// per bucket: total count AND group-segmented within-bucket chunk cursor.
// Group g = chunk & 7 (chunk blocks on XCD g): each bucket's range is subdivided
// [group0 | group1 | ...] so each segment has a single writing XCD in scatter.
__global__ void bucket_totalcursor(unsigned* __restrict__ blockHist,
                                   unsigned* __restrict__ bucketTotal) {
    __shared__ unsigned tmp[512];
    __shared__ unsigned goff[NG];
    int b = blockIdx.x;
    int t = threadIdx.x;
    unsigned v = (t < NCHUNK) ? blockHist[(size_t)b * NCHUNK + t] : 0u;
    tmp[t] = v;
    __syncthreads();
    // group-strided Hillis-Steele: offsets 8,16,...,256 cover all same-group predecessors
    for (int off = 8; off < 512; off <<= 1) {
        unsigned a = (t >= off) ? tmp[t - off] : 0u;
        __syncthreads();
        tmp[t] += a;
        __syncthreads();
    }
    if (t == 0) {
        unsigned acc = 0;
        for (int g = 0; g < NG; ++g) {
            goff[g] = acc;
            int last = g + 8 * ((NCHUNK - 1 - g) / 8);   // last chunk index in group g
            acc += tmp[last];
        }
        bucketTotal[b] = acc;
    }
    __syncthreads();
    if (t < NCHUNK)
        blockHist[(size_t)b * NCHUNK + t] = goff[t & 7] + tmp[t] - v;   // group-local exclusive
}

// exclusive scan over NB2 entries (2 per thread). dst buckets scan to [0,N_EDGES);
// src bucket b base = N_EDGES + srcBase[b]. Also zero-inits hg (folded memset).
__global__ void bucket_scan(const unsigned* __restrict__ bucketTotal, unsigned* __restrict__ bucketBase,
                            float* __restrict__ hg) {
    __shared__ unsigned tmp[1024];
    int t = threadIdx.x;
    if (t < HID) hg[t] = 0.f;
    unsigned v0 = (2 * t < NB2) ? bucketTotal[2 * t] : 0u;
    unsigned v1 = (2 * t + 1 < NB2) ? bucketTotal[2 * t + 1] : 0u;
    unsigned pair = v0 + v1;
    tmp[t] = pair;
    __syncthreads();
    for (int off = 1; off < 1024; off <<= 1) {
        unsigned a = (t >= off) ? tmp[t - off] : 0u;
        __syncthreads();
        tmp[t] += a;
        __syncthreads();
    }
    unsigned excl = tmp[t] - pair;
    if (2 * t < NB2) bucketBase[2 * t] = excl;
    if (2 * t + 1 < NB2) bucketBase[2 * t + 1] = excl + v0;
}

// scatter edges into dst-buckets (uint records) and src low-bits into src-buckets (bytes).
__global__ void bucket_scatter(const int* __restrict__ src, const int* __restrict__ dst,
                               const unsigned* __restrict__ blockHist,
                               const unsigned* __restrict__ bucketBase,
                               unsigned* __restrict__ bucketed,
                               unsigned char* __restrict__ bucketedS) {
    __shared__ unsigned cursor[NB2];
    for (int i = threadIdx.x; i < NB2; i += 512)
        cursor[i] = blockHist[(size_t)i * NCHUNK + blockIdx.x] + bucketBase[i];
    __syncthreads();
    int base = blockIdx.x * CHUNK;
    int lim = min(base + CHUNK, N_EDGES);
    for (int e = base + threadIdx.x; e < lim; e += 512) {
        unsigned d = (unsigned)dst[e];
        unsigned s = (unsigned)src[e];
        unsigned p = atomicAdd(&cursor[d >> BSHIFT], 1u);
        bucketed[p] = ((d & 127u) << 17) | s;   // src < 2^17
        unsigned pS = atomicAdd(&cursor[NBUCK + (s >> BSHIFT)], 1u);
        bucketedS[pS - N_EDGES] = (unsigned char)(s & 127u);
    }
}

// per dst-bucket: row-sort into csrSrc (rows SORTED BY SRC: concurrent gather walks
// sweep src-space in lockstep -> per-phase working set fits the 4MB per-XCD L2),
// rowEnd/normIn; per src-bucket: out-degree -> normOut; folded convert: fp8-encode
// this bucket's 128 feature rows into buf0; pad rows of both buffers zeroed.
__global__ void bucket_place(const unsigned* __restrict__ bucketed,
                             const unsigned char* __restrict__ bucketedS,
                             const unsigned* __restrict__ bucketBase,
                             int* __restrict__ csrSrc, unsigned* __restrict__ rowEnd,
                             float* __restrict__ normIn, float* __restrict__ normOut,
                             const float* __restrict__ feat,
                             unsigned char* __restrict__ out0, unsigned char* __restrict__ out1) {
    __shared__ unsigned cnt128[128], cur[128], cntS[128];
    __shared__ float noL[128];
    __shared__ unsigned eb[MAXB], ob[MAXB];
    int b = blockIdx.x;
    unsigned s0 = bucketBase[b];
    unsigned s1 = bucketBase[b + 1];   // bucketBase[NBUCK] == N_EDGES (src bucket 0 base)
    int cnt = (int)(s1 - s0);
    bool fits = cnt <= MAXB;
    int t = threadIdx.x;
    if (t < 128) { cnt128[t] = 0u; cntS[t] = 0u; }
    __syncthreads();
    for (int i = t; i < cnt; i += 512) {
        unsigned v = bucketed[s0 + i];
        if (fits) eb[i] = v;
        atomicAdd(&cnt128[v >> 17], 1u);
    }
    {   // src-degree count for this bucket (independent work, same barriers)
        unsigned z0 = bucketBase[NBUCK + b] - N_EDGES;
        unsigned z1 = (b + 1 < NBUCK) ? (bucketBase[NBUCK + b + 1] - N_EDGES) : (unsigned)N_EDGES;
        for (unsigned i = z0 + t; i < z1; i += 512)
            atomicAdd(&cntS[bucketedS[i]], 1u);
    }
    __syncthreads();
    unsigned deg = (t < 128) ? cnt128[t] : 0u;
    __syncthreads();
    for (int off = 1; off < 128; off <<= 1) {
        unsigned a = (t < 128 && t >= off) ? cnt128[t - off] : 0u;
        __syncthreads();
        if (t < 128) cnt128[t] += a;
        __syncthreads();
    }
    if (t < 128) {
        unsigned incl = cnt128[t];
        cur[t] = incl - deg;               // local exclusive
        unsigned o = cntS[t];
        float no = o ? rsqrtf((float)o) : 0.0f;
        noL[t] = no;
        int node = b * 128 + t;
        if (node < N_NODES) {
            rowEnd[node] = s0 + incl;      // global inclusive prefix
            normIn[node] = deg ? rsqrtf((float)deg) : 0.0f;
            normOut[node] = no;
        }
    }
    __syncthreads();
    if (fits) {
        for (int i = t; i < cnt; i += 512) {
            unsigned v = eb[i];
            unsigned p = atomicAdd(&cur[v >> 17], 1u);
            ob[p] = v & 0x1FFFFu;
        }
        __syncthreads();
        // sort each row's segment ascending by src (one row per thread, insertion sort):
        // makes concurrent gather walks sweep src-space in lockstep (L2-band locality)
        if (t < 128) {
            int a0 = (int)(cnt128[t] - deg);   // cnt128 = inclusive prefix; deg saved above
            int b0 = (int)cnt128[t];
            for (int i = a0 + 1; i < b0; ++i) {
                unsigned key = ob[i];
                int j = i - 1;
                while (j >= a0 && ob[j] > key) { ob[j + 1] = ob[j]; --j; }
                ob[j + 1] = key;
            }
        }
        __syncthreads();
        for (int i = t; i < cnt; i += 512)
            csrSrc[s0 + i] = (int)ob[i];
    } else {
        for (int i = t; i < cnt; i += 512) {
            unsigned v = bucketed[s0 + i];
            unsigned p = atomicAdd(&cur[v >> 17], 1u);
            csrSrc[s0 + p] = (int)(v & 0x1FFFFu);
        }
    }
    // ---- folded convert: this bucket's rows -> fp8 buf0 (pads zeroed in both bufs) ----
    for (int idx = t; idx < 128 * 16; idx += 512) {
        int r = idx >> 4, j = idx & 15;
        int row = b * 128 + r;
        if (row >= N_PAD) continue;
        if (row >= N_NODES) {
            ((uint2*)out0)[(size_t)row * 16 + j] = make_uint2(0u, 0u);
            ((uint2*)out1)[(size_t)row * 16 + j] = make_uint2(0u, 0u);
            continue;
        }
        float no = noL[r];
        float4 v0 = ((const float4*)feat)[(size_t)row * 32 + j * 2];
        float4 v1 = ((const float4*)feat)[(size_t)row * 32 + j * 2 + 1];
        unsigned lo = 0, hi = 0;
        lo = __builtin_amdgcn_cvt_pk_fp8_f32(v0.x * no, v0.y * no, lo, false);
        lo = __builtin_amdgcn_cvt_pk_fp8_f32(v0.z * no, v0.w * no, lo, true);
        hi = __builtin_amdgcn_cvt_pk_fp8_f32(v1.x * no, v1.y * no, hi, false);
        hi = __builtin_amdgcn_cvt_pk_fp8_f32(v1.z * no, v1.w * no, hi, true);
        ((uint2*)out0)[(size_t)row * 16 + j] = make_uint2(lo, hi);
    }
}

// ============ datapath ============

// accumulate one fp8 row chunk (16 values / lane) into 8 f32x2 accumulators (v_pk_add_f32)
__device__ __forceinline__ void accq(f32x2* a, uint4 v) {
    a[0] += __builtin_amdgcn_cvt_pk_f32_fp8(v.x, false);
    a[1] += __builtin_amdgcn_cvt_pk_f32_fp8(v.x, true);
    a[2] += __builtin_amdgcn_cvt_pk_f32_fp8(v.y, false);
    a[3] += __builtin_amdgcn_cvt_pk_f32_fp8(v.y, true);
    a[4] += __builtin_amdgcn_cvt_pk_f32_fp8(v.z, false);
    a[5] += __builtin_amdgcn_cvt_pk_f32_fp8(v.z, true);
    a[6] += __builtin_amdgcn_cvt_pk_f32_fp8(v.w, false);
    a[7] += __builtin_amdgcn_cvt_pk_f32_fp8(v.w, true);
}

// ============ fused gather(fp8) + MFMA(bf16) + epilogue ============
// Round-1 measured-optimal gather: 8-lane slots, one row per slot per pass,
// 4 edges per vmcnt window (1 aligned int4 idx + 4 dwordx4 gathers), LDS-staged
// edge indices, branchless tail via zeroed pad row. VGPR 64 -> 8 waves/SIMD.
// LDS ~22.4 KB (ECAP 1184; csLDS aliased onto eb) -> 7 blocks/CU.
// hgOut==null: store fp8 h' rows (scaled by postScale if non-null).
// hgOut!=null: skip stores; column-sum the relu output into hgOut (mean fusion).
__launch_bounds__(256)
__global__ void fused_layer(const unsigned char* __restrict__ h,
                            const int* __restrict__ csrSrc,
                            const unsigned* __restrict__ rowEnd,
                            const unsigned short* __restrict__ Wp,
                            const float* __restrict__ bias,
                            const float* __restrict__ normIn,
                            const float* __restrict__ postScale,
                            unsigned char* __restrict__ Out,
                            float* __restrict__ hgOut) {
    __shared__ unsigned short Ml[64 * LROW];        // 17408 B, bf16 staging
    __shared__ __align__(16) int eb[ECAP + 4];      // staged edge indices (+align slack)
    __shared__ unsigned reLDS[65];                  // rowEnd for rows [rowBase-1, rowBase+63]
    float* csLDS = (float*)eb;                      // aliased: eb dead after gather phase
    int tid = threadIdx.x;
    int rowBase = blockIdx.x * 64;

    unsigned startE = rowBase ? rowEnd[rowBase - 1] : 0u;
    unsigned endE = rowEnd[min(rowBase + 63, N_NODES - 1)];
    int cnt = (int)(endE - startE);
    bool fits = cnt <= ECAP;

    if (tid < 65) {
        int r = rowBase - 1 + tid;
        reLDS[tid] = (r < 0) ? 0u : rowEnd[r < N_NODES ? r : N_NODES - 1];
    }
    if (fits) {
        for (int i = tid; i < cnt; i += 256) eb[i] = csrSrc[startE + i];
    }
    __syncthreads();

    int slot = tid >> 3, lane8 = tid & 7;           // 32 slots x 8 lanes
    unsigned lo = (unsigned)lane8 << 4;             // 16 B per lane within 128 B row
    unsigned mclamp = (cnt > 0) ? (unsigned)(cnt - 1) : 0u;
    unsigned mclampAl = mclamp & ~3u;               // aligned clamp for int4 LDS reads

    auto gatherRows = [&](auto E4) {
#pragma unroll
        for (int j = 0; j < 2; ++j) {
            int rloc = slot + 32 * j;
            f32x2 a[8];
#pragma unroll
            for (int q = 0; q < 8; ++q) a[q] = (f32x2){0.f, 0.f};
            unsigned e0 = reLDS[rloc] - startE;
            unsigned e1 = reLDS[rloc + 1] - startE;
            unsigned len = e1 - e0;
            for (unsigned k = e0 & ~3u; k < e1; k += 4) {
                int4 q = E4(k);
                // validity via unsigned wrap: (k+i - e0) < len; invalid -> zeroed pad row
                int s0 = (k + 0u - e0 < len) ? q.x : N_NODES;
                int s1 = (k + 1u - e0 < len) ? q.y : N_NODES;
                int s2 = (k + 2u - e0 < len) ? q.z : N_NODES;
                int s3 = (k + 3u - e0 < len) ? q.w : N_NODES;
                uint4 v0 = *(const uint4*)(h + (((size_t)(unsigned)s0) << 7) + lo);
                uint4 v1 = *(const uint4*)(h + (((size_t)(unsigned)s1) << 7) + lo);
                uint4 v2 = *(const uint4*)(h + (((size_t)(unsigned)s2) << 7) + lo);
                uint4 v3 = *(const uint4*)(h + (((size_t)(unsigned)s3) << 7) + lo);
                accq(a, v0); accq(a, v1); accq(a, v2); accq(a, v3);
            }
            unsigned short* mp = &Ml[rloc * LROW + lane8 * 16];
            uint4 o0, o1;
            o0.x = (unsigned)f2bf(a[0].x) | ((unsigned)f2bf(a[0].y) << 16);
            o0.y = (unsigned)f2bf(a[1].x) | ((unsigned)f2bf(a[1].y) << 16);
            o0.z = (unsigned)f2bf(a[2].x) | ((unsigned)f2bf(a[2].y) << 16);
            o0.w = (unsigned)f2bf(a[3].x) | ((unsigned)f2bf(a[3].y) << 16);
            o1.x = (unsigned)f2bf(a[4].x) | ((unsigned)f2bf(a[4].y) << 16);
            o1.y = (unsigned)f2bf(a[5].x) | ((unsigned)f2bf(a[5].y) << 16);
            o1.z = (unsigned)f2bf(a[6].x) | ((unsigned)f2bf(a[6].y) << 16);
            o1.w = (unsigned)f2bf(a[7].x) | ((unsigned)f2bf(a[7].y) << 16);
            *(uint4*)mp = o0;
            *(uint4*)(mp + 8) = o1;
        }
    };

    if (fits) {
        // k is 16B-aligned; eb has +4 slack; predicates mask garbage lanes
        gatherRows([&](unsigned k) { return *(const int4*)&eb[min(k, mclampAl)]; });
    } else {
        gatherRows([&](unsigned k) {
            int4 r;
            r.x = csrSrc[startE + min(k + 0u, mclamp)];
            r.y = csrSrc[startE + min(k + 1u, mclamp)];
            r.z = csrSrc[startE + min(k + 2u, mclamp)];
            r.w = csrSrc[startE + min(k + 3u, mclamp)];
            return r;
        });
    }
    __syncthreads();
    // eb is dead from here; csLDS (aliased) may be initialized
    if (hgOut != nullptr && tid < 128) csLDS[tid] = 0.f;

    int wave = tid >> 6, lane = tid & 63;
    int mrow = lane & 15, quad = lane >> 4;
    int rloc = wave * 16 + mrow;
    short8 afr[4];
#pragma unroll
    for (int kt = 0; kt < 4; ++kt)
        afr[kt] = *(const short8*)&Ml[rloc * LROW + kt * 32 + quad * 8];

    f32x4 acc[8];
#pragma unroll
    for (int nt = 0; nt < 8; ++nt) {
        f32x4 c = {0.f, 0.f, 0.f, 0.f};
#pragma unroll
        for (int kt = 0; kt < 4; ++kt) {
            short8 b = *(const short8*)&Wp[(size_t)((nt * 4 + kt) * 64 + lane) * 8];
            c = __builtin_amdgcn_mfma_f32_16x16x32_bf16(afr[kt], b, c, 0, 0, 0);
        }
        acc[nt] = c;
    }

    int col0 = lane & 15;
    if (hgOut == nullptr) {
#pragma unroll
        for (int r = 0; r < 4; ++r) {
            int row = rowBase + wave * 16 + quad * 4 + r;
            if (row >= N_NODES) continue;
            float ni = normIn[row];
            float po = postScale ? postScale[row] : 1.0f;
#pragma unroll
            for (int nt = 0; nt < 8; ++nt) {
                float v = fmaxf(fmaf(acc[nt][r], ni, bias[nt * 16 + col0]), 0.f) * po;
                Out[(size_t)row * 128 + nt * 16 + col0] = f2fp8(v);
            }
        }
    } else {
        __syncthreads();   // csLDS zero-init visible before atomics
#pragma unroll
        for (int nt = 0; nt < 8; ++nt) {
            float s = 0.f;
#pragma unroll
            for (int r = 0; r < 4; ++r) {
                int row = rowBase + wave * 16 + quad * 4 + r;
                if (row < N_NODES) {
                    float ni = normIn[row];
                    s += fmaxf(fmaf(acc[nt][r], ni, bias[nt * 16 + col0]), 0.f);
                }
            }
            s += __shfl_xor(s, 16, 64);
            s += __shfl_xor(s, 32, 64);
            if (quad == 0) atomicAdd(&csLDS[nt * 16 + col0], s);
        }
        __syncthreads();
        if (tid < 128) atomicAdd(&hgOut[tid], csLDS[tid]);
    }
}

__global__ void final_kernel(const float* __restrict__ hg, const float* __restrict__ Wr,
                             const float* __restrict__ br, float* __restrict__ out) {
    int j = threadIdx.x;
    if (j < N_PRED) {
        float acc = br[j];
        const float inv = 1.0f / (float)N_NODES;
        for (int k = 0; k < HID; ++k)
            acc = fmaf(hg[k] * inv, Wr[k * N_PRED + j], acc);
        out[j] = acc;
    }
}

extern "C" void kernel_launch(void* const* d_in, const int* in_sizes, int n_in,
                              void* d_out, int out_size, void* d_ws, size_t ws_size,
                              hipStream_t stream) {
    const float* features = (const float*)d_in[0];
    const float* W0 = (const float*)d_in[1];
    const float* b0 = (const float*)d_in[2];
    const float* W1 = (const float*)d_in[3];
    const float* b1 = (const float*)d_in[4];
    const float* W2 = (const float*)d_in[5];
    const float* b2 = (const float*)d_in[6];
    const float* Wr = (const float*)d_in[7];
    const float* br = (const float*)d_in[8];
    const int* src = (const int*)d_in[9];
    const int* dst = (const int*)d_in[10];
    float* out = (float*)d_out;

    char* ws = (char*)d_ws;
    size_t off = 0;
    auto alloc = [&](size_t bytes) -> void* {
        void* p = ws + off;
        off = (off + bytes + 255) & ~(size_t)255;
        return p;
    };
    unsigned char* buf0 = (unsigned char*)alloc((size_t)N_PAD * HID);   // 12.8 MB fp8
    unsigned char* buf1 = (unsigned char*)alloc((size_t)N_PAD * HID);
    unsigned short* Wp0 = (unsigned short*)alloc(128 * 128 * 2);
    unsigned short* Wp1 = (unsigned short*)alloc(128 * 128 * 2);
    unsigned short* Wp2 = (unsigned short*)alloc(128 * 128 * 2);
    float* normOut = (float*)alloc(N_NODES * 4);
    float* normIn = (float*)alloc(N_NODES * 4);
    unsigned* rowEnd = (unsigned*)alloc(N_NODES * 4);
    unsigned* blockHist = (unsigned*)alloc((size_t)NB2 * NCHUNK * 4);   // 2.45 MB
    unsigned* bucketTotal = (unsigned*)alloc(NB2 * 4);
    unsigned* bucketBase = (unsigned*)alloc((NB2 + 1) * 4);
    unsigned* bucketed = (unsigned*)alloc((size_t)N_EDGES * 4);
    unsigned char* bucketedS = (unsigned char*)alloc((size_t)N_EDGES);
    int* csrSrc = (int*)alloc((size_t)N_EDGES * 4);
    float* hg = (float*)alloc(HID * 4);

    bucket_hist<<<NCHUNK + 12, 512, 0, stream>>>((const int4*)src, (const int4*)dst, blockHist,
                                                 W0, W1, W2, Wp0, Wp1, Wp2);
    bucket_totalcursor<<<NB2, 512, 0, stream>>>(blockHist, bucketTotal);
    bucket_scan<<<1, 1024, 0, stream>>>(bucketTotal, bucketBase, hg);
    bucket_scatter<<<NCHUNK, 512, 0, stream>>>(src, dst, blockHist, bucketBase,
                                               bucketed, bucketedS);
    bucket_place<<<NBUCK, 512, 0, stream>>>(bucketed, bucketedS, bucketBase,
                                            csrSrc, rowEnd, normIn, normOut,
                                            features, buf0, buf1);

    int fusedGrid = (N_NODES + 63) / 64;   // 1563

    fused_layer<<<fusedGrid, 256, 0, stream>>>(buf0, csrSrc, rowEnd, Wp0, b0, normIn, normOut,
                                               buf1, (float*)nullptr);
    fused_layer<<<fusedGrid, 256, 0, stream>>>(buf1, csrSrc, rowEnd, Wp1, b1, normIn, normOut,
                                               buf0, (float*)nullptr);
    fused_layer<<<fusedGrid, 256, 0, stream>>>(buf0, csrSrc, rowEnd, Wp2, b2, normIn,
                                               (const float*)nullptr, (unsigned char*)nullptr, hg);

    final_kernel<<<1, 64, 0, stream>>>(hg, Wr, br, out);
}

// Round 10
// 304.615 us; speedup vs baseline: 1.1033x; 1.1033x over previous
//
#include <hip/hip_runtime.h>

#define N_NODES 100000
#define N_PAD   100032
#define N_EDGES 1600000
#define HID 128
#define N_PRED 8

#define BSHIFT 7                       // 128 nodes per bucket
#define NBUCK  782                     // ceil(100000/128)
#define NB2    1564                    // dst buckets ++ src buckets
#define CHUNK  4096                    // edges per sort block
#define NCHUNK 391                     // ceil(1600000/4096)
#define NG     8                       // XCD groups (block->XCD ~ blockIdx%8)
#define MAXB   3072                    // LDS capacity per bucket (avg 2047)
#define ECAP   1184                    // LDS edge-index cap per 64-row block (avg 1024, sigma 32)

#define LROW 136                       // LDS row stride in shorts (128 + 8 pad)

typedef __attribute__((ext_vector_type(8))) short short8;
typedef __attribute__((ext_vector_type(4))) float f32x4;
typedef __attribute__((ext_vector_type(2))) float f32x2;

__device__ __forceinline__ unsigned short f2bf(float f) {
    union { float f; unsigned u; } c; c.f = f;
    unsigned u = c.u;
    u += 0x7fffu + ((u >> 16) & 1u);   // RNE
    return (unsigned short)(u >> 16);
}

__device__ __forceinline__ unsigned char f2fp8(float v) {
    unsigned w = __builtin_amdgcn_cvt_pk_fp8_f32(v, v, 0, false);
    return (unsigned char)(w & 0xff);
}

// ============ CSR build: dual bucket sort (dst for CSR, src for out-degree) ============

// blocks [0,NCHUNK): per-chunk histogram of dst buckets [0,NBUCK) and src buckets [NBUCK,NB2)
// blocks [NCHUNK, NCHUNK+12): repack 3 weights (fp32 KxN) into bf16 B-fragment order
__global__ void bucket_hist(const int4* __restrict__ src4, const int4* __restrict__ dst4,
                            unsigned* __restrict__ blockHist,
                            const float* __restrict__ W0, const float* __restrict__ W1,
                            const float* __restrict__ W2,
                            unsigned short* __restrict__ Wp0, unsigned short* __restrict__ Wp1,
                            unsigned short* __restrict__ Wp2) {
    if (blockIdx.x >= NCHUNK) {        // weight repack: 4 blocks x 512 thr per weight
        int rel = blockIdx.x - NCHUNK;
        int which = rel >> 2;
        const float* W = which == 0 ? W0 : which == 1 ? W1 : W2;
        unsigned short* Wp = which == 0 ? Wp0 : which == 1 ? Wp1 : Wp2;
        int tid = (rel & 3) * 512 + threadIdx.x;   // [0,2048)
        int tile = tid >> 6, lane = tid & 63;
        int n_tile = tile >> 2, k_tile = tile & 3;
        int n = n_tile * 16 + (lane & 15);
        int k0 = k_tile * 32 + (lane >> 4) * 8;
        unsigned short v[8];
#pragma unroll
        for (int j = 0; j < 8; ++j)
            v[j] = f2bf(W[(size_t)(k0 + j) * 128 + n]);
        uint4 o;
        o.x = (unsigned)v[0] | ((unsigned)v[1] << 16);
        o.y = (unsigned)v[2] | ((unsigned)v[3] << 16);
        o.z = (unsigned)v[4] | ((unsigned)v[5] << 16);
        o.w = (unsigned)v[6] | ((unsigned)v[7] << 16);
        *(uint4*)&Wp[(size_t)(tile * 64 + lane) * 8] = o;
        return;
    }
    __shared__ unsigned hist[NB2];
    for (int i = threadIdx.x; i < NB2; i += 512) hist[i] = 0u;
    __syncthreads();
    int base4 = blockIdx.x * (CHUNK / 4);
    int lim4 = min(base4 + CHUNK / 4, N_EDGES / 4);
    for (int e = base4 + threadIdx.x; e < lim4; e += 512) {
        int4 d = dst4[e];
        int4 s = src4[e];
        atomicAdd(&hist[((unsigned)d.x) >> BSHIFT], 1u);
        atomicAdd(&hist[((unsigned)d.y) >> BSHIFT], 1u);
        atomicAdd(&hist[((unsigned)d.z) >> BSHIFT], 1u);
        atomicAdd(&hist[((unsigned)d.w) >> BSHIFT], 1u);
        atomicAdd(&hist[NBUCK + (((unsigned)s.x) >> BSHIFT)], 1u);
        atomicAdd(&hist[NBUCK + (((unsigned)s.y) >> BSHIFT)], 1u);
        atomicAdd(&hist[NBUCK + (((unsigned)s.z) >> BSHIFT)], 1u);
        atomicAdd(&hist[NBUCK + (((unsigned)s.w) >> BSHIFT)], 1u);
    }
    __syncthreads();
    for (int i = threadIdx.x; i < NB2; i += 512)
        blockHist[(size_t)i * NCHUNK + blockIdx.x] = hist[i];   // bucket-major
}

// per bucket: total count AND group-segmented within-bucket chunk cursor.
// Group g = chunk & 7 (chunk blocks on XCD g): each bucket's range is subdivided
// [group0 | group1 | ...] so each segment has a single writing XCD in scatter.
__global__ void bucket_totalcursor(unsigned* __restrict__ blockHist,
                                   unsigned* __restrict__ bucketTotal) {
    __shared__ unsigned tmp[512];
    __shared__ unsigned goff[NG];
    int b = blockIdx.x;
    int t = threadIdx.x;
    unsigned v = (t < NCHUNK) ? blockHist[(size_t)b * NCHUNK + t] : 0u;
    tmp[t] = v;
    __syncthreads();
    // group-strided Hillis-Steele: offsets 8,16,...,256 cover all same-group predecessors
    for (int off = 8; off < 512; off <<= 1) {
        unsigned a = (t >= off) ? tmp[t - off] : 0u;
        __syncthreads();
        tmp[t] += a;
        __syncthreads();
    }
    if (t == 0) {
        unsigned acc = 0;
        for (int g = 0; g < NG; ++g) {
            goff[g] = acc;
            int last = g + 8 * ((NCHUNK - 1 - g) / 8);   // last chunk index in group g
            acc += tmp[last];
        }
        bucketTotal[b] = acc;
    }
    __syncthreads();
    if (t < NCHUNK)
        blockHist[(size_t)b * NCHUNK + t] = goff[t & 7] + tmp[t] - v;   // group-local exclusive
}

// exclusive scan over NB2 entries (2 per thread). dst buckets scan to [0,N_EDGES);
// src bucket b base = N_EDGES + srcBase[b]. Also zero-inits hg (folded memset).
__global__ void bucket_scan(const unsigned* __restrict__ bucketTotal, unsigned* __restrict__ bucketBase,
                            float* __restrict__ hg) {
    __shared__ unsigned tmp[1024];
    int t = threadIdx.x;
    if (t < HID) hg[t] = 0.f;
    unsigned v0 = (2 * t < NB2) ? bucketTotal[2 * t] : 0u;
    unsigned v1 = (2 * t + 1 < NB2) ? bucketTotal[2 * t + 1] : 0u;
    unsigned pair = v0 + v1;
    tmp[t] = pair;
    __syncthreads();
    for (int off = 1; off < 1024; off <<= 1) {
        unsigned a = (t >= off) ? tmp[t - off] : 0u;
        __syncthreads();
        tmp[t] += a;
        __syncthreads();
    }
    unsigned excl = tmp[t] - pair;
    if (2 * t < NB2) bucketBase[2 * t] = excl;
    if (2 * t + 1 < NB2) bucketBase[2 * t + 1] = excl + v0;
}

// scatter edges into dst-buckets (uint records) and src low-bits into src-buckets (bytes).
__global__ void bucket_scatter(const int* __restrict__ src, const int* __restrict__ dst,
                               const unsigned* __restrict__ blockHist,
                               const unsigned* __restrict__ bucketBase,
                               unsigned* __restrict__ bucketed,
                               unsigned char* __restrict__ bucketedS) {
    __shared__ unsigned cursor[NB2];
    for (int i = threadIdx.x; i < NB2; i += 512)
        cursor[i] = blockHist[(size_t)i * NCHUNK + blockIdx.x] + bucketBase[i];
    __syncthreads();
    int base = blockIdx.x * CHUNK;
    int lim = min(base + CHUNK, N_EDGES);
    for (int e = base + threadIdx.x; e < lim; e += 512) {
        unsigned d = (unsigned)dst[e];
        unsigned s = (unsigned)src[e];
        unsigned p = atomicAdd(&cursor[d >> BSHIFT], 1u);
        bucketed[p] = ((d & 127u) << 17) | s;   // src < 2^17
        unsigned pS = atomicAdd(&cursor[NBUCK + (s >> BSHIFT)], 1u);
        bucketedS[pS - N_EDGES] = (unsigned char)(s & 127u);
    }
}

// per dst-bucket: row-sort into csrSrc + rowEnd/normIn; per src-bucket: out-degree
// -> normOut; folded convert: fp8-encode this bucket's 128 feature rows into buf0;
// pad rows of both buffers zeroed.
__global__ void bucket_place(const unsigned* __restrict__ bucketed,
                             const unsigned char* __restrict__ bucketedS,
                             const unsigned* __restrict__ bucketBase,
                             int* __restrict__ csrSrc, unsigned* __restrict__ rowEnd,
                             float* __restrict__ normIn, float* __restrict__ normOut,
                             const float* __restrict__ feat,
                             unsigned char* __restrict__ out0, unsigned char* __restrict__ out1) {
    __shared__ unsigned cnt128[128], cur[128], cntS[128];
    __shared__ float noL[128];
    __shared__ unsigned eb[MAXB], ob[MAXB];
    int b = blockIdx.x;
    unsigned s0 = bucketBase[b];
    unsigned s1 = bucketBase[b + 1];   // bucketBase[NBUCK] == N_EDGES (src bucket 0 base)
    int cnt = (int)(s1 - s0);
    bool fits = cnt <= MAXB;
    int t = threadIdx.x;
    if (t < 128) { cnt128[t] = 0u; cntS[t] = 0u; }
    __syncthreads();
    for (int i = t; i < cnt; i += 512) {
        unsigned v = bucketed[s0 + i];
        if (fits) eb[i] = v;
        atomicAdd(&cnt128[v >> 17], 1u);
    }
    {   // src-degree count for this bucket (independent work, same barriers)
        unsigned z0 = bucketBase[NBUCK + b] - N_EDGES;
        unsigned z1 = (b + 1 < NBUCK) ? (bucketBase[NBUCK + b + 1] - N_EDGES) : (unsigned)N_EDGES;
        for (unsigned i = z0 + t; i < z1; i += 512)
            atomicAdd(&cntS[bucketedS[i]], 1u);
    }
    __syncthreads();
    unsigned deg = (t < 128) ? cnt128[t] : 0u;
    __syncthreads();
    for (int off = 1; off < 128; off <<= 1) {
        unsigned a = (t < 128 && t >= off) ? cnt128[t - off] : 0u;
        __syncthreads();
        if (t < 128) cnt128[t] += a;
        __syncthreads();
    }
    if (t < 128) {
        unsigned incl = cnt128[t];
        cur[t] = incl - deg;               // local exclusive
        unsigned o = cntS[t];
        float no = o ? rsqrtf((float)o) : 0.0f;
        noL[t] = no;
        int node = b * 128 + t;
        if (node < N_NODES) {
            rowEnd[node] = s0 + incl;      // global inclusive prefix
            normIn[node] = deg ? rsqrtf((float)deg) : 0.0f;
            normOut[node] = no;
        }
    }
    __syncthreads();
    if (fits) {
        for (int i = t; i < cnt; i += 512) {
            unsigned v = eb[i];
            unsigned p = atomicAdd(&cur[v >> 17], 1u);
            ob[p] = v & 0x1FFFFu;
        }
        __syncthreads();
        for (int i = t; i < cnt; i += 512)
            csrSrc[s0 + i] = (int)ob[i];
    } else {
        for (int i = t; i < cnt; i += 512) {
            unsigned v = bucketed[s0 + i];
            unsigned p = atomicAdd(&cur[v >> 17], 1u);
            csrSrc[s0 + p] = (int)(v & 0x1FFFFu);
        }
    }
    // ---- folded convert: this bucket's rows -> fp8 buf0 (pads zeroed in both bufs) ----
    for (int idx = t; idx < 128 * 16; idx += 512) {
        int r = idx >> 4, j = idx & 15;
        int row = b * 128 + r;
        if (row >= N_PAD) continue;
        if (row >= N_NODES) {
            ((uint2*)out0)[(size_t)row * 16 + j] = make_uint2(0u, 0u);
            ((uint2*)out1)[(size_t)row * 16 + j] = make_uint2(0u, 0u);
            continue;
        }
        float no = noL[r];
        float4 v0 = ((const float4*)feat)[(size_t)row * 32 + j * 2];
        float4 v1 = ((const float4*)feat)[(size_t)row * 32 + j * 2 + 1];
        unsigned lo = 0, hi = 0;
        lo = __builtin_amdgcn_cvt_pk_fp8_f32(v0.x * no, v0.y * no, lo, false);
        lo = __builtin_amdgcn_cvt_pk_fp8_f32(v0.z * no, v0.w * no, lo, true);
        hi = __builtin_amdgcn_cvt_pk_fp8_f32(v1.x * no, v1.y * no, hi, false);
        hi = __builtin_amdgcn_cvt_pk_fp8_f32(v1.z * no, v1.w * no, hi, true);
        ((uint2*)out0)[(size_t)row * 16 + j] = make_uint2(lo, hi);
    }
}

// ============ datapath ============

// accumulate one fp8 row chunk (16 values / lane) into 8 f32x2 accumulators (v_pk_add_f32)
__device__ __forceinline__ void accq(f32x2* a, uint4 v) {
    a[0] += __builtin_amdgcn_cvt_pk_f32_fp8(v.x, false);
    a[1] += __builtin_amdgcn_cvt_pk_f32_fp8(v.x, true);
    a[2] += __builtin_amdgcn_cvt_pk_f32_fp8(v.y, false);
    a[3] += __builtin_amdgcn_cvt_pk_f32_fp8(v.y, true);
    a[4] += __builtin_amdgcn_cvt_pk_f32_fp8(v.z, false);
    a[5] += __builtin_amdgcn_cvt_pk_f32_fp8(v.z, true);
    a[6] += __builtin_amdgcn_cvt_pk_f32_fp8(v.w, false);
    a[7] += __builtin_amdgcn_cvt_pk_f32_fp8(v.w, true);
}

// ============ fused gather(fp8) + MFMA(bf16) + epilogue ============
// Round-1 measured-optimal gather: 8-lane slots, one row per slot per pass,
// 4 edges per vmcnt window (1 aligned int4 idx + 4 dwordx4 gathers), LDS-staged
// edge indices, branchless tail via zeroed pad row. VGPR 64 -> 8 waves/SIMD.
// LDS ~22.4 KB (ECAP 1184; csLDS aliased onto eb) -> 7 blocks/CU.
// hgOut==null: store fp8 h' rows (scaled by postScale if non-null).
// hgOut!=null: skip stores; column-sum the relu output into hgOut (mean fusion).
__launch_bounds__(256)
__global__ void fused_layer(const unsigned char* __restrict__ h,
                            const int* __restrict__ csrSrc,
                            const unsigned* __restrict__ rowEnd,
                            const unsigned short* __restrict__ Wp,
                            const float* __restrict__ bias,
                            const float* __restrict__ normIn,
                            const float* __restrict__ postScale,
                            unsigned char* __restrict__ Out,
                            float* __restrict__ hgOut) {
    __shared__ unsigned short Ml[64 * LROW];        // 17408 B, bf16 staging
    __shared__ __align__(16) int eb[ECAP + 4];      // staged edge indices (+align slack)
    __shared__ unsigned reLDS[65];                  // rowEnd for rows [rowBase-1, rowBase+63]
    float* csLDS = (float*)eb;                      // aliased: eb dead after gather phase
    int tid = threadIdx.x;
    int rowBase = blockIdx.x * 64;

    unsigned startE = rowBase ? rowEnd[rowBase - 1] : 0u;
    unsigned endE = rowEnd[min(rowBase + 63, N_NODES - 1)];
    int cnt = (int)(endE - startE);
    bool fits = cnt <= ECAP;

    if (tid < 65) {
        int r = rowBase - 1 + tid;
        reLDS[tid] = (r < 0) ? 0u : rowEnd[r < N_NODES ? r : N_NODES - 1];
    }
    if (fits) {
        for (int i = tid; i < cnt; i += 256) eb[i] = csrSrc[startE + i];
    }
    __syncthreads();

    int slot = tid >> 3, lane8 = tid & 7;           // 32 slots x 8 lanes
    unsigned lo = (unsigned)lane8 << 4;             // 16 B per lane within 128 B row
    unsigned mclamp = (cnt > 0) ? (unsigned)(cnt - 1) : 0u;
    unsigned mclampAl = mclamp & ~3u;               // aligned clamp for int4 LDS reads

    auto gatherRows = [&](auto E4) {
#pragma unroll
        for (int j = 0; j < 2; ++j) {
            int rloc = slot + 32 * j;
            f32x2 a[8];
#pragma unroll
            for (int q = 0; q < 8; ++q) a[q] = (f32x2){0.f, 0.f};
            unsigned e0 = reLDS[rloc] - startE;
            unsigned e1 = reLDS[rloc + 1] - startE;
            unsigned len = e1 - e0;
            for (unsigned k = e0 & ~3u; k < e1; k += 4) {
                int4 q = E4(k);
                // validity via unsigned wrap: (k+i - e0) < len; invalid -> zeroed pad row
                int s0 = (k + 0u - e0 < len) ? q.x : N_NODES;
                int s1 = (k + 1u - e0 < len) ? q.y : N_NODES;
                int s2 = (k + 2u - e0 < len) ? q.z : N_NODES;
                int s3 = (k + 3u - e0 < len) ? q.w : N_NODES;
                uint4 v0 = *(const uint4*)(h + (((size_t)(unsigned)s0) << 7) + lo);
                uint4 v1 = *(const uint4*)(h + (((size_t)(unsigned)s1) << 7) + lo);
                uint4 v2 = *(const uint4*)(h + (((size_t)(unsigned)s2) << 7) + lo);
                uint4 v3 = *(const uint4*)(h + (((size_t)(unsigned)s3) << 7) + lo);
                accq(a, v0); accq(a, v1); accq(a, v2); accq(a, v3);
            }
            unsigned short* mp = &Ml[rloc * LROW + lane8 * 16];
            uint4 o0, o1;
            o0.x = (unsigned)f2bf(a[0].x) | ((unsigned)f2bf(a[0].y) << 16);
            o0.y = (unsigned)f2bf(a[1].x) | ((unsigned)f2bf(a[1].y) << 16);
            o0.z = (unsigned)f2bf(a[2].x) | ((unsigned)f2bf(a[2].y) << 16);
            o0.w = (unsigned)f2bf(a[3].x) | ((unsigned)f2bf(a[3].y) << 16);
            o1.x = (unsigned)f2bf(a[4].x) | ((unsigned)f2bf(a[4].y) << 16);
            o1.y = (unsigned)f2bf(a[5].x) | ((unsigned)f2bf(a[5].y) << 16);
            o1.z = (unsigned)f2bf(a[6].x) | ((unsigned)f2bf(a[6].y) << 16);
            o1.w = (unsigned)f2bf(a[7].x) | ((unsigned)f2bf(a[7].y) << 16);
            *(uint4*)mp = o0;
            *(uint4*)(mp + 8) = o1;
        }
    };

    if (fits) {
        // k is 16B-aligned; eb has +4 slack; predicates mask garbage lanes
        gatherRows([&](unsigned k) { return *(const int4*)&eb[min(k, mclampAl)]; });
    } else {
        gatherRows([&](unsigned k) {
            int4 r;
            r.x = csrSrc[startE + min(k + 0u, mclamp)];
            r.y = csrSrc[startE + min(k + 1u, mclamp)];
            r.z = csrSrc[startE + min(k + 2u, mclamp)];
            r.w = csrSrc[startE + min(k + 3u, mclamp)];
            return r;
        });
    }
    __syncthreads();
    // eb is dead from here; csLDS (aliased) may be initialized
    if (hgOut != nullptr && tid < 128) csLDS[tid] = 0.f;

    int wave = tid >> 6, lane = tid & 63;
    int mrow = lane & 15, quad = lane >> 4;
    int rloc = wave * 16 + mrow;
    short8 afr[4];
#pragma unroll
    for (int kt = 0; kt < 4; ++kt)
        afr[kt] = *(const short8*)&Ml[rloc * LROW + kt * 32 + quad * 8];

    f32x4 acc[8];
#pragma unroll
    for (int nt = 0; nt < 8; ++nt) {
        f32x4 c = {0.f, 0.f, 0.f, 0.f};
#pragma unroll
        for (int kt = 0; kt < 4; ++kt) {
            short8 b = *(const short8*)&Wp[(size_t)((nt * 4 + kt) * 64 + lane) * 8];
            c = __builtin_amdgcn_mfma_f32_16x16x32_bf16(afr[kt], b, c, 0, 0, 0);
        }
        acc[nt] = c;
    }

    int col0 = lane & 15;
    if (hgOut == nullptr) {
#pragma unroll
        for (int r = 0; r < 4; ++r) {
            int row = rowBase + wave * 16 + quad * 4 + r;
            if (row >= N_NODES) continue;
            float ni = normIn[row];
            float po = postScale ? postScale[row] : 1.0f;
#pragma unroll
            for (int nt = 0; nt < 8; ++nt) {
                float v = fmaxf(fmaf(acc[nt][r], ni, bias[nt * 16 + col0]), 0.f) * po;
                Out[(size_t)row * 128 + nt * 16 + col0] = f2fp8(v);
            }
        }
    } else {
        __syncthreads();   // csLDS zero-init visible before atomics
#pragma unroll
        for (int nt = 0; nt < 8; ++nt) {
            float s = 0.f;
#pragma unroll
            for (int r = 0; r < 4; ++r) {
                int row = rowBase + wave * 16 + quad * 4 + r;
                if (row < N_NODES) {
                    float ni = normIn[row];
                    s += fmaxf(fmaf(acc[nt][r], ni, bias[nt * 16 + col0]), 0.f);
                }
            }
            s += __shfl_xor(s, 16, 64);
            s += __shfl_xor(s, 32, 64);
            if (quad == 0) atomicAdd(&csLDS[nt * 16 + col0], s);
        }
        __syncthreads();
        if (tid < 128) atomicAdd(&hgOut[tid], csLDS[tid]);
    }
}

__global__ void final_kernel(const float* __restrict__ hg, const float* __restrict__ Wr,
                             const float* __restrict__ br, float* __restrict__ out) {
    int j = threadIdx.x;
    if (j < N_PRED) {
        float acc = br[j];
        const float inv = 1.0f / (float)N_NODES;
        for (int k = 0; k < HID; ++k)
            acc = fmaf(hg[k] * inv, Wr[k * N_PRED + j], acc);
        out[j] = acc;
    }
}

extern "C" void kernel_launch(void* const* d_in, const int* in_sizes, int n_in,
                              void* d_out, int out_size, void* d_ws, size_t ws_size,
                              hipStream_t stream) {
    const float* features = (const float*)d_in[0];
    const float* W0 = (const float*)d_in[1];
    const float* b0 = (const float*)d_in[2];
    const float* W1 = (const float*)d_in[3];
    const float* b1 = (const float*)d_in[4];
    const float* W2 = (const float*)d_in[5];
    const float* b2 = (const float*)d_in[6];
    const float* Wr = (const float*)d_in[7];
    const float* br = (const float*)d_in[8];
    const int* src = (const int*)d_in[9];
    const int* dst = (const int*)d_in[10];
    float* out = (float*)d_out;

    char* ws = (char*)d_ws;
    size_t off = 0;
    auto alloc = [&](size_t bytes) -> void* {
        void* p = ws + off;
        off = (off + bytes + 255) & ~(size_t)255;
        return p;
    };
    unsigned char* buf0 = (unsigned char*)alloc((size_t)N_PAD * HID);   // 12.8 MB fp8
    unsigned char* buf1 = (unsigned char*)alloc((size_t)N_PAD * HID);
    unsigned short* Wp0 = (unsigned short*)alloc(128 * 128 * 2);
    unsigned short* Wp1 = (unsigned short*)alloc(128 * 128 * 2);
    unsigned short* Wp2 = (unsigned short*)alloc(128 * 128 * 2);
    float* normOut = (float*)alloc(N_NODES * 4);
    float* normIn = (float*)alloc(N_NODES * 4);
    unsigned* rowEnd = (unsigned*)alloc(N_NODES * 4);
    unsigned* blockHist = (unsigned*)alloc((size_t)NB2 * NCHUNK * 4);   // 2.45 MB
    unsigned* bucketTotal = (unsigned*)alloc(NB2 * 4);
    unsigned* bucketBase = (unsigned*)alloc((NB2 + 1) * 4);
    unsigned* bucketed = (unsigned*)alloc((size_t)N_EDGES * 4);
    unsigned char* bucketedS = (unsigned char*)alloc((size_t)N_EDGES);
    int* csrSrc = (int*)alloc((size_t)N_EDGES * 4);
    float* hg = (float*)alloc(HID * 4);

    bucket_hist<<<NCHUNK + 12, 512, 0, stream>>>((const int4*)src, (const int4*)dst, blockHist,
                                                 W0, W1, W2, Wp0, Wp1, Wp2);
    bucket_totalcursor<<<NB2, 512, 0, stream>>>(blockHist, bucketTotal);
    bucket_scan<<<1, 1024, 0, stream>>>(bucketTotal, bucketBase, hg);
    bucket_scatter<<<NCHUNK, 512, 0, stream>>>(src, dst, blockHist, bucketBase,
                                               bucketed, bucketedS);
    bucket_place<<<NBUCK, 512, 0, stream>>>(bucketed, bucketedS, bucketBase,
                                            csrSrc, rowEnd, normIn, normOut,
                                            features, buf0, buf1);

    int fusedGrid = (N_NODES + 63) / 64;   // 1563

    fused_layer<<<fusedGrid, 256, 0, stream>>>(buf0, csrSrc, rowEnd, Wp0, b0, normIn, normOut,
                                               buf1, (float*)nullptr);
    fused_layer<<<fusedGrid, 256, 0, stream>>>(buf1, csrSrc, rowEnd, Wp1, b1, normIn, normOut,
                                               buf0, (float*)nullptr);
    fused_layer<<<fusedGrid, 256, 0, stream>>>(buf0, csrSrc, rowEnd, Wp2, b2, normIn,
                                               (const float*)nullptr, (unsigned char*)nullptr, hg);

    final_kernel<<<1, 64, 0, stream>>>(hg, Wr, br, out);
}